// Round 2
// baseline (258.868 us; speedup 1.0000x reference)
//
#include <hip/hip_runtime.h>

// out[b][i][j] = (j == indices[i]) ? grad[b][i] : 0
// shapes: grad (8, 4096) f32, indices (4096,) int, out (8, 4096, 2048) f32.
// One block per (b,i) row; 512 threads x float4 = 2048 floats per row.
// Pure write-stream: 256 MiB out, ~0.14 MiB in -> HBM-write-bound.

#define ROWS_PER_B 4096
#define NEWDIM     2048

typedef float f32x4 __attribute__((ext_vector_type(4)));  // native vec: OK for nontemporal builtin

__global__ __launch_bounds__(512)
void ReduceMaxGrad_53833120088407_kernel(const float* __restrict__ grad,
                                         const int*  __restrict__ indices,
                                         float*      __restrict__ out) {
    const int row = blockIdx.x;                 // b * 4096 + i
    const int i   = row & (ROWS_PER_B - 1);     // row index within batch
    const int t   = threadIdx.x;                // 0..511 -> one float4 each

    const int   idx = indices[i];               // broadcast load (L1 hit)
    const float g   = grad[row];                // broadcast load (L1 hit)

    f32x4 v = (f32x4)(0.f);
    if ((idx >> 2) == t) {
        v[idx & 3] = g;                         // exactly one lane per row
    }

    f32x4* o = (f32x4*)out + (size_t)row * (NEWDIM / 4) + t;
    __builtin_nontemporal_store(v, o);          // streaming: skip L2 retention
}

extern "C" void kernel_launch(void* const* d_in, const int* in_sizes, int n_in,
                              void* d_out, int out_size, void* d_ws, size_t ws_size,
                              hipStream_t stream) {
    const float* grad    = (const float*)d_in[0];   // (8, 4096) f32
    const int*   indices = (const int*)d_in[1];     // (4096,) int32
    float*       out     = (float*)d_out;           // (8, 4096, 2048) f32

    const int n_rows = in_sizes[0];                 // 8 * 4096 = 32768
    ReduceMaxGrad_53833120088407_kernel<<<dim3(n_rows), dim3(512), 0, stream>>>(
        grad, indices, out);
}

// Round 3
// 255.489 us; speedup vs baseline: 1.0132x; 1.0132x over previous
//
#include <hip/hip_runtime.h>

// out[b][i][j] = (j == indices[i]) ? grad[b][i] : 0
// shapes: grad (8, 4096) f32, indices (4096,) int, out (8, 4096, 2048) f32.
// Pure 256 MiB write-stream -> HBM-write-bound, target 6.3 TB/s (= fill rate).
//
// R3 structure: 4096 blocks x 512 threads; each block owns 8 contiguous rows
// (64 KiB contiguous). All 8 rows' (idx, grad) scalar loads are hoisted up
// front, then 8 independent dwordx4 stores per thread issue back-to-back --
// latency-hiding the uniform loads that serialized the R2 one-store-per-wave
// version. Plain stores (not nt) to match fillBuffer's known-good 6.3 TB/s path.

#define ROWS_PER_B     4096
#define NEWDIM         2048
#define ROWS_PER_BLOCK 8

typedef float f32x4 __attribute__((ext_vector_type(4)));

__global__ __launch_bounds__(512)
void ReduceMaxGrad_53833120088407_kernel(const float* __restrict__ grad,
                                         const int*  __restrict__ indices,
                                         float*      __restrict__ out) {
    const int t    = threadIdx.x;                     // 0..511 -> one float4 per row
    const int row0 = blockIdx.x * ROWS_PER_BLOCK;     // first of 8 contiguous rows

    int   idx[ROWS_PER_BLOCK];
    float g[ROWS_PER_BLOCK];
#pragma unroll
    for (int r = 0; r < ROWS_PER_BLOCK; ++r) {
        const int row = row0 + r;
        idx[r] = indices[row & (ROWS_PER_B - 1)];     // uniform s_load, all issued up front
        g[r]   = grad[row];
    }

    f32x4* o = (f32x4*)out + (size_t)row0 * (NEWDIM / 4) + t;
#pragma unroll
    for (int r = 0; r < ROWS_PER_BLOCK; ++r) {
        f32x4 v = (f32x4)(0.f);
        if ((idx[r] >> 2) == t) v[idx[r] & 3] = g[r]; // exactly one lane per row
        o[(size_t)r * (NEWDIM / 4)] = v;              // 8 back-to-back dwordx4 stores
    }
}

extern "C" void kernel_launch(void* const* d_in, const int* in_sizes, int n_in,
                              void* d_out, int out_size, void* d_ws, size_t ws_size,
                              hipStream_t stream) {
    const float* grad    = (const float*)d_in[0];   // (8, 4096) f32
    const int*   indices = (const int*)d_in[1];     // (4096,) int32
    float*       out     = (float*)d_out;           // (8, 4096, 2048) f32

    const int n_rows   = in_sizes[0];               // 8 * 4096 = 32768
    const int n_blocks = n_rows / ROWS_PER_BLOCK;   // 4096
    ReduceMaxGrad_53833120088407_kernel<<<dim3(n_blocks), dim3(512), 0, stream>>>(
        grad, indices, out);
}

// Round 4
// 254.707 us; speedup vs baseline: 1.0163x; 1.0031x over previous
//
#include <hip/hip_runtime.h>

// out[b][i][j] = (j == indices[i]) ? grad[b][i] : 0
// grad (8,4096) f32, indices (4096,) int, out (8,4096,2048) f32 = 256 MiB.
// Pure write-stream; floor = 268 MB / 6.5 TB/s ~= 41 us.
//
// R4: fill-kernel-style structure. 1024 blocks x 512 threads = 8192 waves =
// exactly 32 waves/CU in ONE dispatch round (no block turnover). Each block
// owns 32 contiguous rows (256 KiB); inner loop does 8 rows/iter with the
// NEXT iter's (idx, grad) scalar loads prefetched before the current iter's
// 8 back-to-back dwordx4 stores -- zero exposed load latency.

#define ROWS_PER_B 4096
#define NEWDIM     2048
#define F4_PER_ROW (NEWDIM / 4)   // 512
#define RPI        8              // rows per inner iteration
#define ITERS      4              // iterations per block -> 32 rows/block

typedef float f32x4 __attribute__((ext_vector_type(4)));

__global__ __launch_bounds__(512)
void ReduceMaxGrad_53833120088407_kernel(const float* __restrict__ grad,
                                         const int*  __restrict__ indices,
                                         float*      __restrict__ out) {
    const int t    = threadIdx.x;                  // 0..511 -> one float4 per row
    const int row0 = blockIdx.x * (RPI * ITERS);   // 32 contiguous rows per block

    int   idx[RPI];
    float g[RPI];
#pragma unroll
    for (int r = 0; r < RPI; ++r) {                // prefetch group 0
        idx[r] = indices[(row0 + r) & (ROWS_PER_B - 1)];
        g[r]   = grad[row0 + r];
    }

    f32x4* o = (f32x4*)out + (size_t)row0 * F4_PER_ROW + t;

#pragma unroll
    for (int it = 0; it < ITERS; ++it) {
        int   nidx[RPI];
        float ng[RPI];
        if (it + 1 < ITERS) {                      // prefetch group it+1
            const int nrow0 = row0 + (it + 1) * RPI;
#pragma unroll
            for (int r = 0; r < RPI; ++r) {
                nidx[r] = indices[(nrow0 + r) & (ROWS_PER_B - 1)];
                ng[r]   = grad[nrow0 + r];
            }
        }
#pragma unroll
        for (int r = 0; r < RPI; ++r) {            // 8 back-to-back dwordx4 stores
            f32x4 v = (f32x4)(0.f);
            if ((idx[r] >> 2) == t) v[idx[r] & 3] = g[r];
            o[(size_t)(it * RPI + r) * F4_PER_ROW] = v;
        }
        if (it + 1 < ITERS) {
#pragma unroll
            for (int r = 0; r < RPI; ++r) { idx[r] = nidx[r]; g[r] = ng[r]; }
        }
    }
}

extern "C" void kernel_launch(void* const* d_in, const int* in_sizes, int n_in,
                              void* d_out, int out_size, void* d_ws, size_t ws_size,
                              hipStream_t stream) {
    const float* grad    = (const float*)d_in[0];   // (8, 4096) f32
    const int*   indices = (const int*)d_in[1];     // (4096,) int32
    float*       out     = (float*)d_out;           // (8, 4096, 2048) f32

    const int n_rows   = in_sizes[0];               // 32768
    const int n_blocks = n_rows / (RPI * ITERS);    // 1024
    ReduceMaxGrad_53833120088407_kernel<<<dim3(n_blocks), dim3(512), 0, stream>>>(
        grad, indices, out);
}